// Round 9
// baseline (212.676 us; speedup 1.0000x reference)
//
#include <hip/hip_runtime.h>

#define B_DIM 4096
#define H_DIM 1024
#define K_DIM 2048   // IN + H
#define NT (K_DIM / 32)   // 64 K-tiles of BK=32

typedef unsigned short u16;
typedef unsigned int u32;
typedef __attribute__((ext_vector_type(8))) short short8;
typedef __attribute__((ext_vector_type(4))) float f32x4;

typedef const __attribute__((address_space(1))) void* gas_ptr;
typedef __attribute__((address_space(3))) void* las_ptr;

#define WT_ELEMS (4 * H_DIM * K_DIM)       // 8.39M u16
#define AC_ELEMS (B_DIM * K_DIM)           // 8.39M u16
#define WS_NEEDED ((size_t)(WT_ELEMS + AC_ELEMS) * 2)   // 33.55 MB

__device__ __forceinline__ void gl_lds16(const u16* g, u16* l) {
    __builtin_amdgcn_global_load_lds((gas_ptr)g, (las_ptr)l, 16, 0, 0);
}
__device__ __forceinline__ float bf2f(u16 v) {
    return __builtin_bit_cast(float, (u32)((u32)v << 16));
}
__device__ __forceinline__ u16 f2bf(float f) {
    u32 u = __builtin_bit_cast(u32, f);
    return (u16)((u + 0x7fffu + ((u >> 16) & 1u)) >> 16);
}
__device__ __forceinline__ float sigm(float x) { return 1.0f / (1.0f + __expf(-x)); }
__device__ __forceinline__ float tanh_f(float x) { return 1.0f - 2.0f / (__expf(2.0f * x) + 1.0f); }

// ---------- consolidated prep (round-5/6/8 verified): 1024 blocks ----------
__global__ __launch_bounds__(256) void prep_all(const float* __restrict__ x, const float* __restrict__ h,
                                                const float* __restrict__ Wf, const float* __restrict__ Wi,
                                                const float* __restrict__ Wg, const float* __restrict__ Wo,
                                                u16* __restrict__ A, u16* __restrict__ Wt) {
    const int t = threadIdx.x;
    if (blockIdx.x < 512) {
#pragma unroll
        for (int it = 0; it < 8; ++it) {
            int e = it * (512 * 256 * 8) + (blockIdx.x * 256 + t) * 8;
            int m = e >> 11, c = e & 2047;
            const float* src = (c < 1024) ? (x + (size_t)m * 1024 + c)
                                          : (h + (size_t)m * 1024 + (c - 1024));
            float4 v0 = ((const float4*)src)[0], v1 = ((const float4*)src)[1];
            short8 q;
            q[0] = (short)f2bf(v0.x); q[1] = (short)f2bf(v0.y); q[2] = (short)f2bf(v0.z); q[3] = (short)f2bf(v0.w);
            q[4] = (short)f2bf(v1.x); q[5] = (short)f2bf(v1.y); q[6] = (short)f2bf(v1.z); q[7] = (short)f2bf(v1.w);
            *(short8*)(A + e) = q;
        }
    } else {
        const int id = (blockIdx.x - 512) * 4 + (t >> 6);   // one 64x64 tile per wave
        const int l = t & 63;
        const int k0 = (id & 31) * 64, n0 = ((id >> 5) & 15) * 64, g = id >> 9;
        const float* W = (g == 0) ? Wf : (g == 1) ? Wi : (g == 2) ? Wg : Wo;
        const int no = (l & 7) * 8;
        const int ko = (l >> 3) * 8;
        float f[8][8];
#pragma unroll
        for (int j = 0; j < 8; ++j) {
            const float4* s = (const float4*)(W + (size_t)(k0 + ko + j) * H_DIM + n0 + no);
            float4 a = s[0], b = s[1];
            f[j][0] = a.x; f[j][1] = a.y; f[j][2] = a.z; f[j][3] = a.w;
            f[j][4] = b.x; f[j][5] = b.y; f[j][6] = b.z; f[j][7] = b.w;
        }
        u16* dst0 = Wt + (size_t)g * ((size_t)H_DIM * K_DIM) + (size_t)(n0 + no) * K_DIM + k0 + ko;
#pragma unroll
        for (int w2 = 0; w2 < 8; ++w2) {
            short8 q;
#pragma unroll
            for (int j = 0; j < 8; ++j) q[j] = (short)f2bf(f[j][w2]);
            *(short8*)(dst0 + (size_t)w2 * K_DIM) = q;
        }
    }
}

// ---------- main fused GEMM + LSTM: 16x16x32 MFMA, 2 blocks/CU, triple-buffer, 1 barrier/tile ----------
// Occupancy experiment: every prior variant ran 8 waves/CU (2/SIMD) and plateaued at
// ~80 us / 35% MfmaUtil. This kernel: BM=256, BN=32 cols x 4 gates (128 eff), BK=32,
// grid 16x32 = 512 blocks = exactly 2 blocks/CU (LDS 72 KiB x 2 = 144 <= 160), 16 waves/CU.
// Per K-tile per wave: 8 ds_read_b128 + 16 INDEPENDENT MFMA (acc[4 mt][4 g]) + 3 gl_lds;
// ONE barrier per tile (64 total). Triple buffer, 2-tile prefetch: stage T(kt+2) during
// kt; close = vmcnt(3) (retires T(kt+1), leaves T(kt+2) in flight) + barrier. Waves slip
// freely inside the tile region (LDS pipe || MFMA pipe || VMEM across waves + blocks).
// Swizzle (4 slots of 8 u16 per 32-k row): phys_slot = k8 ^ ((row>>2)&3), BOTH-SIDES
// (pre-swizzled global source + read index). Within any 16-lane b128 group: 4 slot-groups
// x 4 rows, rows r/r+2 share banks -> exactly 2-way everywhere = free (m136).
// Read-side key: row = {wr*64 + mt*16 + l15 | g*32 + wc*16 + l15} -> (row>>2)&3 =
// (l15>>2)&3 = per-lane constant kq (all other terms are multiples of 4).
// Frag maps + register epilogue (all 4 gates lane-local) carried from the verified r6 kernel.
#define STG(C)                                                            \
    gl_lds16(pa0, smu + (C) * 12288 + t * 8);        pa0 += 32;           \
    gl_lds16(pa1, smu + (C) * 12288 + 4096 + t * 8); pa1 += 32;           \
    gl_lds16(pb0, smu + (C) * 12288 + 8192 + t * 8); pb0 += 32;

#define RD_A4(C)                                                          \
    _Pragma("unroll") for (int mt = 0; mt < 4; ++mt)                      \
        afr[mt] = *(const short8*)&smu[(C) * 12288 +                      \
            (wr * 64 + mt * 16 + l15) * 32 + sl8];

#define RD_BP(C, GP)                                                      \
    _Pragma("unroll") for (int gi = 0; gi < 2; ++gi)                      \
        bfr[gi] = *(const short8*)&smu[(C) * 12288 + 8192 +               \
            (((GP) * 2 + gi) * 32 + wc * 16 + l15) * 32 + sl8];

#define MFMA_H(GP)                                                        \
    _Pragma("unroll") for (int mt = 0; mt < 4; ++mt)                      \
    _Pragma("unroll") for (int gi = 0; gi < 2; ++gi)                      \
        acc[mt][(GP) * 2 + gi] = __builtin_amdgcn_mfma_f32_16x16x32_bf16( \
            afr[mt], bfr[gi], acc[mt][(GP) * 2 + gi], 0, 0, 0);

__global__ __launch_bounds__(512, 4) void lstm_gemm(
    const u16* __restrict__ A, const u16* __restrict__ Wt, const float* __restrict__ c_prev,
    const float* __restrict__ bf_, const float* __restrict__ bi_,
    const float* __restrict__ bg_, const float* __restrict__ bo_,
    float* __restrict__ out) {
    // per buffer (12288 u16 = 24 KB): A [0,8192): m*32 + slot*8 ; B [8192,12288): nrow*32 + slot*8
    __shared__ u16 sm[3][12288];   // 72 KiB -> 2 blocks/CU
    u16* smu = &sm[0][0];

    const int t = threadIdx.x;
    const int w = t >> 6;
    const int l = t & 63;
    const int quad = l >> 4;
    const int l15 = l & 15;
    const int kq = (l15 >> 2) & 3;
    const int sl8 = ((quad ^ kq) & 3) * 8;
    const int wr = w >> 1;          // 0..3: 64-row m-quarter
    const int wc = w & 1;           // 0..1: 16-col h-half
    const int m0 = blockIdx.x * 256;
    const int j0 = blockIdx.y * 32;

    f32x4 acc[4][4];                // [m-tile][gate]
#pragma unroll
    for (int mt = 0; mt < 4; ++mt)
#pragma unroll
        for (int g = 0; g < 4; ++g)
            acc[mt][g] = (f32x4){0.f, 0.f, 0.f, 0.f};

    // Staging source pointers, pre-swizzled (advance 32 u16 per K-tile).
    // A: thread t covers m = i*128 + t>>2, slot = t&3, phys = slot ^ ((m>>2)&3);
    //    (m>>2)&3 == (t>>4)&3 for both halves (128 = 0 mod 4).
    // B: nrow = t>>2 (= g*32 + nc), slot = t&3, phys = slot ^ ((t>>4)&3).
    const int aphys = ((t & 3) ^ ((t >> 4) & 3)) * 8;
    const u16* pa0 = A + (size_t)(m0 + (t >> 2)) * K_DIM + aphys;
    const u16* pa1 = pa0 + (size_t)128 * K_DIM;
    const u16* pb0 = Wt + (size_t)(t >> 7) * ((size_t)H_DIM * K_DIM) +
                     (size_t)(j0 + ((t >> 2) & 31)) * K_DIM + aphys;

    short8 afr[4], bfr[2];

    // prologue: stage T0 -> buf0, T1 -> buf1 (6 gl_lds); wait T0 (3 left = T1)
    STG(0); STG(1);
    asm volatile("s_waitcnt vmcnt(3)" ::: "memory");
    __builtin_amdgcn_s_barrier();

    int c0 = 0, c1 = 1, c2 = 2;
    for (int kt = 0; kt < NT - 2; ++kt) {
        RD_A4(c0); RD_BP(c0, 0);
        STG(c2);                     // stage T(kt+2); overwrites buf read at kt-1 (barrier-separated)
        __builtin_amdgcn_s_setprio(1);
        MFMA_H(0);
        RD_BP(c0, 1);
        MFMA_H(1);
        __builtin_amdgcn_s_setprio(0);
        asm volatile("s_waitcnt vmcnt(3)" ::: "memory");   // T(kt+1) landed; T(kt+2) in flight
        __builtin_amdgcn_s_barrier();
        int tmp = c0; c0 = c1; c1 = c2; c2 = tmp;
    }
    {   // kt = NT-2: no staging; drain T(NT-1)
        RD_A4(c0); RD_BP(c0, 0);
        __builtin_amdgcn_s_setprio(1);
        MFMA_H(0);
        RD_BP(c0, 1);
        MFMA_H(1);
        __builtin_amdgcn_s_setprio(0);
        asm volatile("s_waitcnt vmcnt(0)" ::: "memory");
        __builtin_amdgcn_s_barrier();
    }
    {   // kt = NT-1 (buffer c1), nothing outstanding
        RD_A4(c1); RD_BP(c1, 0);
        MFMA_H(0);
        RD_BP(c1, 1);
        MFMA_H(1);
    }

    // -------- register epilogue: all 4 gates of each output element in one lane --------
    // C/D map (16x16): col = lane&15, row = quad*4 + reg
    const int col = j0 + wc * 16 + l15;
    const float bF = bf_[col], bI = bi_[col], bG = bg_[col], bO = bo_[col];
#pragma unroll
    for (int mt = 0; mt < 4; ++mt) {
        const int rowbase = m0 + wr * 64 + mt * 16 + quad * 4;
        float cp[4];
#pragma unroll
        for (int rr = 0; rr < 4; ++rr)
            cp[rr] = c_prev[(size_t)(rowbase + rr) * H_DIM + col];
#pragma unroll
        for (int rr = 0; rr < 4; ++rr) {
            float fv = sigm(acc[mt][0][rr] + bF);
            float iv = sigm(acc[mt][1][rr] + bI);
            float gv = tanh_f(acc[mt][2][rr] + bG);
            float ov = sigm(acc[mt][3][rr] + bO);
            float cn = fv * cp[rr] + iv * gv;
            float hn = ov * tanh_f(cn);
            size_t idx = (size_t)(rowbase + rr) * H_DIM + col;
            out[idx] = hn;
            out[(size_t)B_DIM * H_DIM + idx] = cn;
        }
    }
}

// ---------- fallback (verified): used only if ws too small ----------
__global__ __launch_bounds__(256) void lstm_f32(
    const float* __restrict__ x, const float* __restrict__ h_prev, const float* __restrict__ c_prev,
    const float* __restrict__ Wf, const float* __restrict__ Wi, const float* __restrict__ Wg, const float* __restrict__ Wo,
    const float* __restrict__ bf_, const float* __restrict__ bi_, const float* __restrict__ bg_, const float* __restrict__ bo_,
    float* __restrict__ out) {
    __shared__ u16 smem[16384];
    u16* sA = smem;
    u16* sB = smem + 4096;

    const int t = threadIdx.x;
    const int w = t >> 6;
    const int l = t & 63;
    const int quad = l >> 4;
    const int l15 = l & 15;
    const int wr = w >> 1;
    const int wc = w & 1;
    const int m0 = blockIdx.x * 128;
    const int j0 = blockIdx.y * 32;

    const int arow = t >> 1;
    const int akh = (t & 1) * 16;
    const int r7 = t & 127;
    const int bk = r7 >> 2;
    const int bn8 = (r7 & 3) * 8;
    const int kswz = ((((bk >> 3) ^ (bn8 >> 3)) << 3) | (bk & 7));
    const float* WpA = (t < 128) ? Wf : Wi;
    const float* WpB = (t < 128) ? Wg : Wo;
    const int gA = (t >> 7);
    const int gB = 2 + (t >> 7);

    f32x4 acc[2][4][2];
#pragma unroll
    for (int gi = 0; gi < 2; ++gi)
#pragma unroll
        for (int mi = 0; mi < 4; ++mi)
#pragma unroll
            for (int ni = 0; ni < 2; ++ni)
                acc[gi][mi][ni] = (f32x4){0.f, 0.f, 0.f, 0.f};

    for (int kt = 0; kt < K_DIM / 32; ++kt) {
        const float* srcA = (kt < 32) ? x : h_prev;
        const int koff = (kt & 31) * 32;
        __syncthreads();

        const float4* ap = (const float4*)(srcA + (size_t)(m0 + arow) * H_DIM + koff + akh);
        float4 a0 = ap[0], a1 = ap[1], a2 = ap[2], a3 = ap[3];
        short8 p0, p1;
        p0[0] = (short)f2bf(a0.x); p0[1] = (short)f2bf(a0.y); p0[2] = (short)f2bf(a0.z); p0[3] = (short)f2bf(a0.w);
        p0[4] = (short)f2bf(a1.x); p0[5] = (short)f2bf(a1.y); p0[6] = (short)f2bf(a1.z); p0[7] = (short)f2bf(a1.w);
        p1[0] = (short)f2bf(a2.x); p1[1] = (short)f2bf(a2.y); p1[2] = (short)f2bf(a2.z); p1[3] = (short)f2bf(a2.w);
        p1[4] = (short)f2bf(a3.x); p1[5] = (short)f2bf(a3.y); p1[6] = (short)f2bf(a3.z); p1[7] = (short)f2bf(a3.w);
        *(short8*)(sA + arow * 32 + akh) = p0;
        *(short8*)(sA + arow * 32 + akh + 8) = p1;

        const float* gpA = WpA + (size_t)(kt * 32 + bk) * H_DIM + j0 + bn8;
        const float* gpB = WpB + (size_t)(kt * 32 + bk) * H_DIM + j0 + bn8;
        float4 c0 = *(const float4*)gpA, c1 = *(const float4*)(gpA + 4);
        float4 d0 = *(const float4*)gpB, d1 = *(const float4*)(gpB + 4);
        sB[gA * 1024 + (bn8 + 0) * 32 + kswz] = f2bf(c0.x);
        sB[gA * 1024 + (bn8 + 1) * 32 + kswz] = f2bf(c0.y);
        sB[gA * 1024 + (bn8 + 2) * 32 + kswz] = f2bf(c0.z);
        sB[gA * 1024 + (bn8 + 3) * 32 + kswz] = f2bf(c0.w);
        sB[gA * 1024 + (bn8 + 4) * 32 + kswz] = f2bf(c1.x);
        sB[gA * 1024 + (bn8 + 5) * 32 + kswz] = f2bf(c1.y);
        sB[gA * 1024 + (bn8 + 6) * 32 + kswz] = f2bf(c1.z);
        sB[gA * 1024 + (bn8 + 7) * 32 + kswz] = f2bf(c1.w);
        sB[gB * 1024 + (bn8 + 0) * 32 + kswz] = f2bf(d0.x);
        sB[gB * 1024 + (bn8 + 1) * 32 + kswz] = f2bf(d0.y);
        sB[gB * 1024 + (bn8 + 2) * 32 + kswz] = f2bf(d0.z);
        sB[gB * 1024 + (bn8 + 3) * 32 + kswz] = f2bf(d0.w);
        sB[gB * 1024 + (bn8 + 4) * 32 + kswz] = f2bf(d1.x);
        sB[gB * 1024 + (bn8 + 5) * 32 + kswz] = f2bf(d1.y);
        sB[gB * 1024 + (bn8 + 6) * 32 + kswz] = f2bf(d1.z);
        sB[gB * 1024 + (bn8 + 7) * 32 + kswz] = f2bf(d1.w);
        __syncthreads();

        short8 bfr[2][2];
#pragma unroll
        for (int gi = 0; gi < 2; ++gi) {
            int g = wc * 2 + gi;
#pragma unroll
            for (int ni = 0; ni < 2; ++ni) {
                int n = ni * 16 + l15;
                bfr[gi][ni] = *(const short8*)(sB + g * 1024 + n * 32 + ((quad ^ (n >> 3)) * 8));
            }
        }
#pragma unroll
        for (int mi = 0; mi < 4; ++mi) {
            int m = wr * 64 + mi * 16 + l15;
            short8 afr = *(const short8*)(sA + m * 32 + quad * 8);
#pragma unroll
            for (int gi = 0; gi < 2; ++gi)
#pragma unroll
                for (int ni = 0; ni < 2; ++ni)
                    acc[gi][mi][ni] =
                        __builtin_amdgcn_mfma_f32_16x16x32_bf16(afr, bfr[gi][ni], acc[gi][mi][ni], 0, 0, 0);
        }
    }

    __syncthreads();
#pragma unroll
    for (int gi = 0; gi < 2; ++gi) {
        int g = wc * 2 + gi;
        const float* bp = (g == 0) ? bf_ : (g == 1) ? bi_ : (g == 2) ? bg_ : bo_;
#pragma unroll
        for (int ni = 0; ni < 2; ++ni) {
            int col = ni * 16 + l15;
            float bias = bp[j0 + col];
#pragma unroll
            for (int mi = 0; mi < 4; ++mi)
#pragma unroll
                for (int rr = 0; rr < 4; ++rr) {
                    int row = wr * 64 + mi * 16 + quad * 4 + rr;
                    float v = acc[gi][mi][ni][rr] + bias;
                    v = (g == 2) ? tanh_f(v) : sigm(v);
                    smem[g * 4096 + row * 32 + col] = f2bf(v);
                }
        }
    }
    __syncthreads();

    const int col = t & 31;
    const int rb = t >> 5;
#pragma unroll
    for (int p = 0; p < 16; ++p) {
        int row = p * 8 + rb;
        float fv = bf2f(smem[0 * 4096 + row * 32 + col]);
        float iv = bf2f(smem[1 * 4096 + row * 32 + col]);
        float gv = bf2f(smem[2 * 4096 + row * 32 + col]);
        float ov = bf2f(smem[3 * 4096 + row * 32 + col]);
        size_t oidx = (size_t)(m0 + row) * H_DIM + j0 + col;
        float cp = c_prev[oidx];
        float cn = fv * cp + iv * gv;
        float hn = ov * tanh_f(cn);
        out[oidx] = hn;
        out[(size_t)B_DIM * H_DIM + oidx] = cn;
    }
}

extern "C" void kernel_launch(void* const* d_in, const int* in_sizes, int n_in,
                              void* d_out, int out_size, void* d_ws, size_t ws_size,
                              hipStream_t stream) {
    const float* x   = (const float*)d_in[0];
    const float* hp  = (const float*)d_in[1];
    const float* cp  = (const float*)d_in[2];
    const float* Wf  = (const float*)d_in[3];
    const float* bf_ = (const float*)d_in[4];
    const float* Wi  = (const float*)d_in[5];
    const float* bi_ = (const float*)d_in[6];
    const float* Wg  = (const float*)d_in[7];
    const float* bg_ = (const float*)d_in[8];
    const float* Wo  = (const float*)d_in[9];
    const float* bo_ = (const float*)d_in[10];

    if (ws_size >= WS_NEEDED) {
        u16* Wt = (u16*)d_ws;
        u16* Ac = (u16*)d_ws + WT_ELEMS;
        prep_all<<<dim3(1024), dim3(256), 0, stream>>>(x, hp, Wf, Wi, Wg, Wo, Ac, Wt);
        lstm_gemm<<<dim3(B_DIM / 256, H_DIM / 32), dim3(512), 0, stream>>>(
            Ac, Wt, cp, bf_, bi_, bg_, bo_, (float*)d_out);
    } else {
        lstm_f32<<<dim3(B_DIM / 128, H_DIM / 32), dim3(256), 0, stream>>>(
            x, hp, cp, Wf, Wi, Wg, Wo, bf_, bi_, bg_, bo_, (float*)d_out);
    }
}